// Round 10
// baseline (1195.667 us; speedup 1.0000x reference)
//
#include <hip/hip_runtime.h>
#include <math.h>

typedef __attribute__((ext_vector_type(8))) short bf16x8;
typedef __attribute__((ext_vector_type(4))) short bf16x4;
typedef __attribute__((ext_vector_type(4))) float f32x4;

static __device__ __forceinline__ unsigned short f2bf(float x){
    union{float f; unsigned u;} v; v.f = x;
    unsigned r = v.u + 0x7fffu + ((v.u >> 16) & 1u);
    return (unsigned short)(r >> 16);
}
static __device__ __forceinline__ unsigned cvtpk(float lo, float hi){
    unsigned r;
    asm("v_cvt_pk_bf16_f32 %0, %1, %2" : "=v"(r) : "v"(lo), "v"(hi));
    return r;
}
static __device__ __forceinline__ float bflo(unsigned u){
    union{unsigned x; float f;} v; v.x = u << 16; return v.f;
}
static __device__ __forceinline__ float bfhi(unsigned u){
    union{unsigned x; float f;} v; v.x = u & 0xffff0000u; return v.f;
}

// ------------------------------------------------- QKV (K,V stored bf16) ---
__global__ __launch_bounds__(128)
void qkv_kernel(const float* __restrict__ h,
                const float* __restrict__ Wq, const float* __restrict__ Wk,
                const float* __restrict__ Wv,
                float* __restrict__ Qb, unsigned short* __restrict__ Kb16,
                unsigned short* __restrict__ Vb16)
{
    __shared__ float hl[16 * 128];
    const int t  = threadIdx.x;
    const int n0 = blockIdx.x * 16;

    const float4* hg4 = (const float4*)(h + (size_t)n0 * 128);
    float4* hl4 = (float4*)hl;
    #pragma unroll
    for (int i = 0; i < 4; ++i) hl4[i * 128 + t] = hg4[i * 128 + t];
    __syncthreads();

    #pragma unroll
    for (int m = 0; m < 3; ++m) {
        const float* W = (m == 0 ? Wq : (m == 1 ? Wk : Wv)) + t * 128;
        float acc[16];
        #pragma unroll
        for (int n = 0; n < 16; ++n) acc[n] = 0.f;
        for (int kc = 0; kc < 32; ++kc) {
            const float4 w = *(const float4*)(W + kc * 4);
            #pragma unroll
            for (int n = 0; n < 16; ++n) {
                const float4 x = *(const float4*)&hl[n * 128 + kc * 4];
                acc[n] += w.x * x.x + w.y * x.y + w.z * x.z + w.w * x.w;
            }
        }
        if (m == 0) {
            float* o = Qb + (size_t)n0 * 128 + t;
            #pragma unroll
            for (int n = 0; n < 16; ++n) o[(size_t)n * 128] = acc[n];
        } else {
            unsigned short* o = (m == 1 ? Kb16 : Vb16) + (size_t)n0 * 128 + t;
            #pragma unroll
            for (int n = 0; n < 16; ++n) o[(size_t)n * 128] = f2bf(acc[n]);
        }
    }
}

// ------------------------------------------------------------- CSR build ---
__global__ void hist_kernel(const int* __restrict__ ei, int* __restrict__ cnt, int EDG)
{
    const int stride = gridDim.x * blockDim.x;
    for (int e = blockIdx.x * blockDim.x + threadIdx.x; e < EDG; e += stride)
        atomicAdd(&cnt[ei[EDG + e]], 1);
}

__global__ __launch_bounds__(1024)
void scan_a(const int* __restrict__ cnt, int* __restrict__ bsum, int n)
{
    __shared__ int tmp[1024];
    const int t = threadIdx.x;
    const int i = blockIdx.x * 1024 + t;
    tmp[t] = (i < n) ? cnt[i] : 0;
    __syncthreads();
    for (int d = 512; d > 0; d >>= 1) {
        if (t < d) tmp[t] += tmp[t + d];
        __syncthreads();
    }
    if (t == 0) bsum[blockIdx.x] = tmp[0];
}

__global__ void scan_b(const int* __restrict__ bsum, int* __restrict__ bbase,
                       int* __restrict__ offs, int nb, int n)
{
    if (threadIdx.x == 0) {
        int run = 0;
        for (int b = 0; b < nb; ++b) { bbase[b] = run; run += bsum[b]; }
        offs[n] = run;
    }
}

__global__ __launch_bounds__(1024)
void scan_c(const int* __restrict__ cnt, const int* __restrict__ bbase,
            int* __restrict__ offs, int n)
{
    __shared__ int tmp[1024];
    const int t = threadIdx.x;
    const int i = blockIdx.x * 1024 + t;
    const int v = (i < n) ? cnt[i] : 0;
    tmp[t] = v;
    __syncthreads();
    for (int d = 1; d < 1024; d <<= 1) {
        const int a = (t >= d) ? tmp[t - d] : 0;
        __syncthreads();
        tmp[t] += a;
        __syncthreads();
    }
    if (i < n) offs[i] = bbase[blockIdx.x] + tmp[t] - v;
}

// consumes cnt (atomicSub -> ends at 0); emits (src, edge) list in CSR order
__global__ void scatter_kernel(const int* __restrict__ ei, const int* __restrict__ offs,
                               int* __restrict__ cnt, int2* __restrict__ elist, int EDG)
{
    const int stride = gridDim.x * blockDim.x;
    for (int e = blockIdx.x * blockDim.x + threadIdx.x; e < EDG; e += stride) {
        const int d = ei[EDG + e];
        const int p = atomicSub(&cnt[d], 1) - 1;
        int2 v; v.x = ei[e]; v.y = e;
        elist[offs[d] + p] = v;
    }
}

// --------------------------------------- fused edge-score + gather (MFMA) --
// Register-diet v4: head-half MFMA split (acc[4]+accb), Q row in per-wave
// LDS (fp32), no eattr prefetch (frv bf16 regs only). bf16 K/V gathers.
// Target natural VGPR <= 80 -> 3 waves/SIMD, 12 waves/CU, no spill.
__global__ __launch_bounds__(256, 3)
void fused_attn(const float* __restrict__ eattr, const int2* __restrict__ elist,
                const int* __restrict__ offs,
                const float* __restrict__ We, const float* __restrict__ Wb,
                const float* __restrict__ bbv,
                const float* __restrict__ Qb, const unsigned short* __restrict__ Kb16,
                const unsigned short* __restrict__ Vb16, const float* __restrict__ h,
                float* __restrict__ x, float* __restrict__ stat, int N, int EDG)
{
    __shared__ unsigned short WeB[128 * 128];  // 32 KB (d,k): byte d*256 + ((2k)^((d&7)<<4))
    __shared__ unsigned short WbB[16 * 128];   // 4 KB; reused as stats scratch at end
    __shared__ float scw[4][16][8];            // per-wave score redistribution
    __shared__ int   srw[4][16];               // per-wave src ids
    __shared__ float qlds[4][128];             // per-wave Q row (fp32)

    const int t = threadIdx.x;
    #pragma unroll
    for (int i = 0; i < 16; ++i) {
        const int idx4 = i * 256 + t;
        const int d = idx4 >> 5, k0 = (idx4 & 31) * 4;
        const float4 wv = *(const float4*)&We[d * 128 + k0];
        bf16x4 p;
        p[0] = (short)f2bf(wv.x); p[1] = (short)f2bf(wv.y);
        p[2] = (short)f2bf(wv.z); p[3] = (short)f2bf(wv.w);
        *(bf16x4*)((char*)WeB + d * 256 + ((2 * k0) ^ ((d & 7) << 4))) = p;
    }
    #pragma unroll
    for (int i = 0; i < 8; ++i) {
        const int idx = i * 256 + t;
        const int r = idx >> 7, k = idx & 127;
        const unsigned short v = (r < 8) ? f2bf(Wb[r * 128 + k]) : (unsigned short)0;
        *(unsigned short*)((char*)WbB + r * 256 + ((2 * k) ^ ((r & 7) << 4))) = v;
    }
    __syncthreads();                            // WeB/WbB ready; read-only in loop

    const int l = t & 63, w = t >> 6;
    const int eloc = l & 15, g4 = l >> 4;
    const int half = l >> 5, q = l & 31;        // PV: lane owns dims 4q..4q+3
    const int hq = q >> 2;
    const int kb_l = g4 * 16;

    float4 sA = {0.f, 0.f, 0.f, 0.f}, sQ2 = {0.f, 0.f, 0.f, 0.f};
    const int GW = gridDim.x * 4;
    for (int node = blockIdx.x * 4 + w; node < N; node += GW) {
        const int beg = offs[node], end = offs[node + 1];

        // stage Q row (fp32) into per-wave LDS
        *(float2*)&qlds[w][2 * l] = *(const float2*)&Qb[(size_t)node * 128 + 2 * l];
        asm volatile("s_waitcnt lgkmcnt(0)" ::: "memory");
        __builtin_amdgcn_sched_barrier(0);

        float4 pv = {0.f, 0.f, 0.f, 0.f};
        float zz = 0.f;

        for (int base = beg; base < end; base += 16) {
            const int cnt = min(16, end - base);
            const int ii = min(base + eloc, EDG - 1);
            const int2 se = elist[ii];

            // ---- per-lane eattr B-fragment: load + immediate bf16 convert --
            bf16x8 frv[4];
            {
                const float* ep = eattr + (size_t)se.y * 128 + g4 * 8;
                #pragma unroll
                for (int ks = 0; ks < 4; ++ks) {
                    const float4 a0 = *(const float4*)(ep + ks * 32);
                    const float4 a1 = *(const float4*)(ep + ks * 32 + 4);
                    union { unsigned u[4]; bf16x8 v; } fr;
                    fr.u[0] = cvtpk(a0.x, a0.y);
                    fr.u[1] = cvtpk(a0.z, a0.w);
                    fr.u[2] = cvtpk(a1.x, a1.y);
                    fr.u[3] = cvtpk(a1.z, a1.w);
                    frv[ks] = fr.v;
                }
            }
            const unsigned short* kr16 = Kb16 + (size_t)se.x * 128 + g4 * 4;

            // ---- MFMA + epilogue in two head-halves (acc[4] live) ----
            f32x4 accb = (f32x4){0.f, 0.f, 0.f, 0.f};
            #pragma unroll
            for (int hp = 0; hp < 2; ++hp) {
                f32x4 acc[4];
                #pragma unroll
                for (int h2 = 0; h2 < 4; ++h2) acc[h2] = (f32x4){0.f, 0.f, 0.f, 0.f};
                #pragma unroll
                for (int ks = 0; ks < 4; ++ks) {
                    const int kb = ks * 64 + kb_l;
                    if (hp == 0) {
                        const bf16x8 abf = *(const bf16x8*)((char*)WbB + eloc * 256 + (kb ^ ((eloc & 7) << 4)));
                        accb = __builtin_amdgcn_mfma_f32_16x16x32_bf16(abf, frv[ks], accb, 0, 0, 0);
                    }
                    #pragma unroll
                    for (int h2 = 0; h2 < 4; ++h2) {
                        const int ar = (hp * 4 + h2) * 16 + eloc;
                        const bf16x8 af = *(const bf16x8*)((char*)WeB + ar * 256 + (kb ^ ((ar & 7) << 4)));
                        acc[h2] = __builtin_amdgcn_mfma_f32_16x16x32_bf16(af, frv[ks], acc[h2], 0, 0, 0);
                    }
                }
                // epilogue for this head half
                float scv[4];
                #pragma unroll
                for (int h2 = 0; h2 < 4; ++h2) {
                    const int hh = hp * 4 + h2;
                    const uint2  k2 = *(const uint2*)(kr16 + hh * 16);
                    const float4 q4 = *(const float4*)&qlds[w][hh * 16 + g4 * 4];
                    float m = acc[h2][0] * (bflo(k2.x) * q4.x)
                            + acc[h2][1] * (bfhi(k2.x) * q4.y)
                            + acc[h2][2] * (bflo(k2.y) * q4.z)
                            + acc[h2][3] * (bfhi(k2.y) * q4.w);
                    m += __shfl_xor(m, 16);
                    m += __shfl_xor(m, 32);
                    const float eb = __shfl(accb[hh & 3], ((hh >> 2) << 4) | eloc);
                    float sc = m * 0.25f + eb + bbv[hh];
                    sc = expf(fminf(fmaxf(sc, -5.f), 5.f));
                    scv[h2] = (eloc < cnt) ? sc : 0.f;   // mask chunk tail
                }
                if (l < 16) {
                    float4 s4 = {scv[0], scv[1], scv[2], scv[3]};
                    *(float4*)&scw[w][l][hp * 4] = s4;
                }
            }
            if (l < 16) srw[w][l] = se.x;
            asm volatile("s_waitcnt lgkmcnt(0)" ::: "memory");
            __builtin_amdgcn_sched_barrier(0);

            // ---- PV: halves alternate CSR slots; lane owns dims 4q..4q+3 --
            int e = half;
            for (; e + 2 < cnt; e += 4) {
                const int   s0 = srw[w][e],     s1 = srw[w][e + 2];
                const float c0 = scw[w][e][hq], c1 = scw[w][e + 2][hq];
                const uint2 u0 = *(const uint2*)(Vb16 + (size_t)s0 * 128 + 4 * q);
                const uint2 u1 = *(const uint2*)(Vb16 + (size_t)s1 * 128 + 4 * q);
                pv.x += bflo(u0.x) * c0 + bflo(u1.x) * c1;
                pv.y += bfhi(u0.x) * c0 + bfhi(u1.x) * c1;
                pv.z += bflo(u0.y) * c0 + bflo(u1.y) * c1;
                pv.w += bfhi(u0.y) * c0 + bfhi(u1.y) * c1;
                zz += c0 + c1;
            }
            for (; e < cnt; e += 2) {
                const int   s0 = srw[w][e];
                const float c0 = scw[w][e][hq];
                const uint2 u0 = *(const uint2*)(Vb16 + (size_t)s0 * 128 + 4 * q);
                pv.x += bflo(u0.x) * c0; pv.y += bfhi(u0.x) * c0;
                pv.z += bflo(u0.y) * c0; pv.w += bfhi(u0.y) * c0;
                zz += c0;
            }
        }

        // merge halves, write x row from half 0
        pv.x += __shfl_xor(pv.x, 32); pv.y += __shfl_xor(pv.y, 32);
        pv.z += __shfl_xor(pv.z, 32); pv.w += __shfl_xor(pv.w, 32);
        zz   += __shfl_xor(zz, 32);
        if (half == 0) {
            const float inv = 1.f / (zz + 1e-6f);
            const float4 hv = *(const float4*)&h[(size_t)node * 128 + 4 * q];
            float4 xv;
            xv.x = hv.x + pv.x * inv; xv.y = hv.y + pv.y * inv;
            xv.z = hv.z + pv.z * inv; xv.w = hv.w + pv.w * inv;
            *(float4*)&x[(size_t)node * 128 + 4 * q] = xv;
            sA.x += xv.x; sA.y += xv.y; sA.z += xv.z; sA.w += xv.w;
            sQ2.x += xv.x * xv.x; sQ2.y += xv.y * xv.y;
            sQ2.z += xv.z * xv.z; sQ2.w += xv.w * xv.w;
        }
    }

    // ---- stats: reuse WbB as scratch (all waves past the loop) ----
    __syncthreads();
    float* wbF = (float*)WbB;                   // 1024 floats
    if (half == 0) {
        *(float4*)&wbF[w * 256 + 4 * q]       = sA;
        *(float4*)&wbF[w * 256 + 128 + 4 * q] = sQ2;
    }
    __syncthreads();
    if (t < 128) {
        float s = 0.f, sq2 = 0.f;
        #pragma unroll
        for (int wi = 0; wi < 4; ++wi) {
            s   += wbF[wi * 256 + t];
            sq2 += wbF[wi * 256 + 128 + t];
        }
        atomicAdd(&stat[t], s);
        atomicAdd(&stat[128 + t], sq2);
    }
}

// ---------------------------------------------------------- BN params ------
__global__ void bn_params(const float* __restrict__ sum, const float* __restrict__ sumsq,
                          const float* __restrict__ gamma, const float* __restrict__ beta,
                          float* __restrict__ a, float* __restrict__ b, float invn)
{
    const int c = threadIdx.x;
    const float mean = sum[c] * invn;
    const float var  = sumsq[c] * invn - mean * mean;
    const float sc   = gamma[c] * rsqrtf(var + 1e-5f);
    a[c] = sc;
    b[c] = beta[c] - mean * sc;
}

// ---------------------------------------------------------------- FFN ------
__global__ __launch_bounds__(128)
void ffn_kernel(const float* __restrict__ x, const float* __restrict__ W1,
                const float* __restrict__ b1, const float* __restrict__ W2,
                const float* __restrict__ b2, const float* __restrict__ par,
                float* __restrict__ zb, float* __restrict__ stat2)
{
    __shared__ float xnl[16 * 128];
    __shared__ float hidl[16 * 256];
    const int t  = threadIdx.x;
    const int n0 = blockIdx.x * 16;

    const float4* xg4 = (const float4*)(x + (size_t)n0 * 128);
    const float4* a4  = (const float4*)par;
    const float4* bv4 = (const float4*)(par + 128);
    float4* xnl4 = (float4*)xnl;
    #pragma unroll
    for (int i = 0; i < 4; ++i) {
        const int idx = i * 128 + t;
        const float4 xv = xg4[idx];
        const float4 av = a4[idx & 31], bv = bv4[idx & 31];
        float4 r;
        r.x = xv.x * av.x + bv.x; r.y = xv.y * av.y + bv.y;
        r.z = xv.z * av.z + bv.z; r.w = xv.w * av.w + bv.w;
        xnl4[idx] = r;
    }
    __syncthreads();

    float acc0[16], acc1[16];
    #pragma unroll
    for (int n = 0; n < 16; ++n) { acc0[n] = 0.f; acc1[n] = 0.f; }
    const float* w0p = W1 + (size_t)t * 128;
    const float* w1p = W1 + (size_t)(t + 128) * 128;
    for (int kc = 0; kc < 32; ++kc) {
        const float4 w0 = *(const float4*)(w0p + kc * 4);
        const float4 w1 = *(const float4*)(w1p + kc * 4);
        #pragma unroll
        for (int n = 0; n < 16; ++n) {
            const float4 xv = *(const float4*)&xnl[n * 128 + kc * 4];
            acc0[n] += w0.x * xv.x + w0.y * xv.y + w0.z * xv.z + w0.w * xv.w;
            acc1[n] += w1.x * xv.x + w1.y * xv.y + w1.z * xv.z + w1.w * xv.w;
        }
    }
    const float bi0 = b1[t], bi1 = b1[t + 128];
    #pragma unroll
    for (int n = 0; n < 16; ++n) {
        hidl[n * 256 + t]       = fmaxf(acc0[n] + bi0, 0.f);
        hidl[n * 256 + 128 + t] = fmaxf(acc1[n] + bi1, 0.f);
    }
    __syncthreads();

    float acc2[16];
    #pragma unroll
    for (int n = 0; n < 16; ++n) acc2[n] = 0.f;
    const float* w2p = W2 + (size_t)t * 256;
    for (int kc = 0; kc < 64; ++kc) {
        const float4 w = *(const float4*)(w2p + kc * 4);
        #pragma unroll
        for (int n = 0; n < 16; ++n) {
            const float4 hv = *(const float4*)&hidl[n * 256 + kc * 4];
            acc2[n] += w.x * hv.x + w.y * hv.y + w.z * hv.z + w.w * hv.w;
        }
    }
    const float bi2 = b2[t];
    float s = 0.f, sq = 0.f;
    float* zo = zb + (size_t)n0 * 128 + t;
    #pragma unroll
    for (int n = 0; n < 16; ++n) {
        const float z = xnl[n * 128 + t] + acc2[n] + bi2;
        zo[(size_t)n * 128] = z;
        s += z; sq += z * z;
    }
    atomicAdd(&stat2[t], s);
    atomicAdd(&stat2[128 + t], sq);
}

// ---------------------------------------------------------- final BN -------
__global__ void final_bn(const float4* __restrict__ zb, const float* __restrict__ pa,
                         const float* __restrict__ pb, float4* __restrict__ out, int total4)
{
    const float4* a4 = (const float4*)pa;
    const float4* b4 = (const float4*)pb;
    const int stride = gridDim.x * blockDim.x;
    for (int i = blockIdx.x * blockDim.x + threadIdx.x; i < total4; i += stride) {
        const float4 z = zb[i];
        const float4 a = a4[i & 31], b = b4[i & 31];
        float4 r;
        r.x = z.x * a.x + b.x; r.y = z.y * a.y + b.y;
        r.z = z.z * a.z + b.z; r.w = z.w * a.w + b.w;
        out[i] = r;
    }
}

// ---------------------------------------------------------------------------
extern "C" void kernel_launch(void* const* d_in, const int* in_sizes, int n_in,
                              void* d_out, int out_size, void* d_ws, size_t ws_size,
                              hipStream_t stream)
{
    const float* h   = (const float*)d_in[0];
    const int*   ei  = (const int*)  d_in[1];
    const float* ea  = (const float*)d_in[2];
    const float* Wq  = (const float*)d_in[3];
    const float* Wk  = (const float*)d_in[4];
    const float* Wv  = (const float*)d_in[5];
    const float* We  = (const float*)d_in[6];
    const float* Wb  = (const float*)d_in[7];
    const float* bbv = (const float*)d_in[8];
    const float* g1  = (const float*)d_in[9];
    const float* be1 = (const float*)d_in[10];
    const float* W1  = (const float*)d_in[11];
    const float* b1  = (const float*)d_in[12];
    const float* W2  = (const float*)d_in[13];
    const float* b2  = (const float*)d_in[14];
    const float* g2  = (const float*)d_in[15];
    const float* be2 = (const float*)d_in[16];
    float* out = (float*)d_out;

    const int N   = in_sizes[0] / 128;
    const int EDG = in_sizes[1] / 2;
    const int NB  = (N + 1023) / 1024;
    const size_t nd = (size_t)N * 128;
    auto al8 = [](size_t v){ return (v + 7) & ~(size_t)7; };

    float* ws = (float*)d_ws;
    const size_t Qo  = 0;                            // Qb fp32; reused as z after fused_attn
    const size_t K16 = nd;                           // Kb16 (nd ushort = nd/2 slots)
    const size_t V16 = nd + nd / 2;                  // Vb16
    const size_t Xo  = 2 * nd;                       // x (attn output)
    const size_t ELo = 3 * nd;                       // elist (EDG int2)
    const size_t OFo = ELo + (size_t)EDG * 2;        // offs (N+1 int)
    const size_t CUo = al8(OFo + (size_t)N + 8);     // counts (N int)
    const size_t BSo = al8(CUo + (size_t)N);         // block sums (NB int)
    const size_t BBo = al8(BSo + (size_t)NB);        // block bases (NB int)
    const size_t STo = al8(BBo + (size_t)NB);        // stats: 512 f32
    const size_t PAR = STo + 512;                    // bn params: 512 f32

    int*  cnt   = (int*)(ws + CUo);
    int*  offs  = (int*)(ws + OFo);
    int*  bsum  = (int*)(ws + BSo);
    int*  bbase = (int*)(ws + BBo);
    int2* elist = (int2*)(ws + ELo);
    unsigned short* kb16 = (unsigned short*)(ws + K16);
    unsigned short* vb16 = (unsigned short*)(ws + V16);

    hipMemsetAsync(cnt, 0, (size_t)N * sizeof(int), stream);
    hipMemsetAsync(ws + STo, 0, 512 * sizeof(float), stream);

    qkv_kernel<<<N / 16, 128, 0, stream>>>(h, Wq, Wk, Wv, ws + Qo, kb16, vb16);

    hist_kernel<<<1024, 256, 0, stream>>>(ei, cnt, EDG);
    scan_a<<<NB, 1024, 0, stream>>>(cnt, bsum, N);
    scan_b<<<1, 64, 0, stream>>>(bsum, bbase, offs, NB, N);
    scan_c<<<NB, 1024, 0, stream>>>(cnt, bbase, offs, N);
    scatter_kernel<<<1024, 256, 0, stream>>>(ei, offs, cnt, elist, EDG);

    fused_attn<<<1024, 256, 0, stream>>>(ea, elist, offs, We, Wb, bbv,
                                         ws + Qo, kb16, vb16, h,
                                         ws + Xo, ws + STo, N, EDG);

    bn_params<<<1, 128, 0, stream>>>(ws + STo, ws + STo + 128, g1, be1,
                                     ws + PAR, ws + PAR + 128, 1.0f / (float)N);
    ffn_kernel<<<N / 16, 128, 0, stream>>>(ws + Xo, W1, b1, W2, b2, ws + PAR,
                                           ws + Qo, ws + STo + 256);
    bn_params<<<1, 128, 0, stream>>>(ws + STo + 256, ws + STo + 384, g2, be2,
                                     ws + PAR + 256, ws + PAR + 384, 1.0f / (float)N);
    final_bn<<<1024, 256, 0, stream>>>((const float4*)(ws + Qo), ws + PAR + 256,
                                       ws + PAR + 384, (float4*)out, N * 32);
}

// Round 11
// 1094.407 us; speedup vs baseline: 1.0925x; 1.0925x over previous
//
#include <hip/hip_runtime.h>
#include <math.h>

typedef __attribute__((ext_vector_type(8))) short bf16x8;
typedef __attribute__((ext_vector_type(4))) short bf16x4;
typedef __attribute__((ext_vector_type(4))) float f32x4;

static __device__ __forceinline__ unsigned short f2bf(float x){
    union{float f; unsigned u;} v; v.f = x;
    unsigned r = v.u + 0x7fffu + ((v.u >> 16) & 1u);
    return (unsigned short)(r >> 16);
}
static __device__ __forceinline__ unsigned cvtpk(float lo, float hi){
    unsigned r;
    asm("v_cvt_pk_bf16_f32 %0, %1, %2" : "=v"(r) : "v"(lo), "v"(hi));
    return r;
}
static __device__ __forceinline__ float bflo(unsigned u){
    union{unsigned x; float f;} v; v.x = u << 16; return v.f;
}
static __device__ __forceinline__ float bfhi(unsigned u){
    union{unsigned x; float f;} v; v.x = u & 0xffff0000u; return v.f;
}

// ------------------------------------------------- QKV (K,V stored bf16) ---
__global__ __launch_bounds__(128)
void qkv_kernel(const float* __restrict__ h,
                const float* __restrict__ Wq, const float* __restrict__ Wk,
                const float* __restrict__ Wv,
                float* __restrict__ Qb, unsigned short* __restrict__ Kb16,
                unsigned short* __restrict__ Vb16)
{
    __shared__ float hl[16 * 128];
    const int t  = threadIdx.x;
    const int n0 = blockIdx.x * 16;

    const float4* hg4 = (const float4*)(h + (size_t)n0 * 128);
    float4* hl4 = (float4*)hl;
    #pragma unroll
    for (int i = 0; i < 4; ++i) hl4[i * 128 + t] = hg4[i * 128 + t];
    __syncthreads();

    #pragma unroll
    for (int m = 0; m < 3; ++m) {
        const float* W = (m == 0 ? Wq : (m == 1 ? Wk : Wv)) + t * 128;
        float acc[16];
        #pragma unroll
        for (int n = 0; n < 16; ++n) acc[n] = 0.f;
        for (int kc = 0; kc < 32; ++kc) {
            const float4 w = *(const float4*)(W + kc * 4);
            #pragma unroll
            for (int n = 0; n < 16; ++n) {
                const float4 x = *(const float4*)&hl[n * 128 + kc * 4];
                acc[n] += w.x * x.x + w.y * x.y + w.z * x.z + w.w * x.w;
            }
        }
        if (m == 0) {
            float* o = Qb + (size_t)n0 * 128 + t;
            #pragma unroll
            for (int n = 0; n < 16; ++n) o[(size_t)n * 128] = acc[n];
        } else {
            unsigned short* o = (m == 1 ? Kb16 : Vb16) + (size_t)n0 * 128 + t;
            #pragma unroll
            for (int n = 0; n < 16; ++n) o[(size_t)n * 128] = f2bf(acc[n]);
        }
    }
}

// ------------------------------------------------------------- CSR build ---
__global__ void hist_kernel(const int* __restrict__ ei, int* __restrict__ cnt, int EDG)
{
    const int stride = gridDim.x * blockDim.x;
    for (int e = blockIdx.x * blockDim.x + threadIdx.x; e < EDG; e += stride)
        atomicAdd(&cnt[ei[EDG + e]], 1);
}

__global__ __launch_bounds__(1024)
void scan_a(const int* __restrict__ cnt, int* __restrict__ bsum, int n)
{
    __shared__ int tmp[1024];
    const int t = threadIdx.x;
    const int i = blockIdx.x * 1024 + t;
    tmp[t] = (i < n) ? cnt[i] : 0;
    __syncthreads();
    for (int d = 512; d > 0; d >>= 1) {
        if (t < d) tmp[t] += tmp[t + d];
        __syncthreads();
    }
    if (t == 0) bsum[blockIdx.x] = tmp[0];
}

__global__ void scan_b(const int* __restrict__ bsum, int* __restrict__ bbase,
                       int* __restrict__ offs, int nb, int n)
{
    if (threadIdx.x == 0) {
        int run = 0;
        for (int b = 0; b < nb; ++b) { bbase[b] = run; run += bsum[b]; }
        offs[n] = run;
    }
}

__global__ __launch_bounds__(1024)
void scan_c(const int* __restrict__ cnt, const int* __restrict__ bbase,
            int* __restrict__ offs, int n)
{
    __shared__ int tmp[1024];
    const int t = threadIdx.x;
    const int i = blockIdx.x * 1024 + t;
    const int v = (i < n) ? cnt[i] : 0;
    tmp[t] = v;
    __syncthreads();
    for (int d = 1; d < 1024; d <<= 1) {
        const int a = (t >= d) ? tmp[t - d] : 0;
        __syncthreads();
        tmp[t] += a;
        __syncthreads();
    }
    if (i < n) offs[i] = bbase[blockIdx.x] + tmp[t] - v;
}

// consumes cnt (atomicSub -> ends at 0); emits (src, edge) list in CSR order
__global__ void scatter_kernel(const int* __restrict__ ei, const int* __restrict__ offs,
                               int* __restrict__ cnt, int2* __restrict__ elist, int EDG)
{
    const int stride = gridDim.x * blockDim.x;
    for (int e = blockIdx.x * blockDim.x + threadIdx.x; e < EDG; e += stride) {
        const int d = ei[EDG + e];
        const int p = atomicSub(&cnt[d], 1) - 1;
        int2 v; v.x = ei[e]; v.y = e;
        elist[offs[d] + p] = v;
    }
}

// --------------------------------------- fused edge-score + gather (MFMA) --
// Round-6 single-pass structure + bf16 K/V + half-split PV + WbB-reuse stats.
// 4 waves/block, 38.25 KB LDS -> 4 blocks/CU if VGPR <= ~85. One wave per
// node (strided). Per 16-edge chunk: eattr B-frags -> bf16 regs, 36 MFMAs
// (all 8 heads, single pass), epilogue with hoistable bf16-K loads, then
// bf16 V[src]*score accumulation.
__global__ __launch_bounds__(256, 3)
void fused_attn(const float* __restrict__ eattr, const int2* __restrict__ elist,
                const int* __restrict__ offs,
                const float* __restrict__ We, const float* __restrict__ Wb,
                const float* __restrict__ bbv,
                const float* __restrict__ Qb, const unsigned short* __restrict__ Kb16,
                const unsigned short* __restrict__ Vb16, const float* __restrict__ h,
                float* __restrict__ x, float* __restrict__ stat, int N, int EDG)
{
    __shared__ unsigned short WeB[128 * 128];  // 32 KB (d,k): byte d*256 + ((2k)^((d&7)<<4))
    __shared__ unsigned short WbB[16 * 128];   // 4 KB; reused as stats scratch at end
    __shared__ float scw[4][16][8];            // per-wave score redistribution
    __shared__ int   srw[4][16];               // per-wave src ids

    const int t = threadIdx.x;
    #pragma unroll
    for (int i = 0; i < 16; ++i) {
        const int idx4 = i * 256 + t;
        const int d = idx4 >> 5, k0 = (idx4 & 31) * 4;
        const float4 wv = *(const float4*)&We[d * 128 + k0];
        bf16x4 p;
        p[0] = (short)f2bf(wv.x); p[1] = (short)f2bf(wv.y);
        p[2] = (short)f2bf(wv.z); p[3] = (short)f2bf(wv.w);
        *(bf16x4*)((char*)WeB + d * 256 + ((2 * k0) ^ ((d & 7) << 4))) = p;
    }
    #pragma unroll
    for (int i = 0; i < 8; ++i) {
        const int idx = i * 256 + t;
        const int r = idx >> 7, k = idx & 127;
        const unsigned short v = (r < 8) ? f2bf(Wb[r * 128 + k]) : (unsigned short)0;
        *(unsigned short*)((char*)WbB + r * 256 + ((2 * k) ^ ((r & 7) << 4))) = v;
    }
    __syncthreads();                            // WeB/WbB ready; read-only in loop

    const int l = t & 63, w = t >> 6;
    const int eloc = l & 15, g4 = l >> 4;
    const int half = l >> 5, q = l & 31;        // PV: lane owns dims 4q..4q+3
    const int hq = q >> 2;
    const int kb_l = g4 * 16;
    float bb[8];
    #pragma unroll
    for (int hh = 0; hh < 8; ++hh) bb[hh] = bbv[hh];

    float4 sA = {0.f, 0.f, 0.f, 0.f}, sQ2 = {0.f, 0.f, 0.f, 0.f};
    const int GW = gridDim.x * 4;
    for (int node = blockIdx.x * 4 + w; node < N; node += GW) {
        const int beg = offs[node], end = offs[node + 1];

        const float* qrow = Qb + (size_t)node * 128 + g4 * 4;
        float4 qv[8];
        #pragma unroll
        for (int hh = 0; hh < 8; ++hh) qv[hh] = *(const float4*)(qrow + hh * 16);

        float4 pv = {0.f, 0.f, 0.f, 0.f};
        float zz = 0.f;

        for (int base = beg; base < end; base += 16) {
            const int cnt = min(16, end - base);
            const int ii = min(base + eloc, EDG - 1);
            const int2 se = elist[ii];

            // ---- per-lane eattr B-fragment: load + immediate bf16 convert --
            bf16x8 frv[4];
            {
                const float* ep = eattr + (size_t)se.y * 128 + g4 * 8;
                #pragma unroll
                for (int ks = 0; ks < 4; ++ks) {
                    const float4 a0 = *(const float4*)(ep + ks * 32);
                    const float4 a1 = *(const float4*)(ep + ks * 32 + 4);
                    union { unsigned u[4]; bf16x8 v; } fr;
                    fr.u[0] = cvtpk(a0.x, a0.y);
                    fr.u[1] = cvtpk(a0.z, a0.w);
                    fr.u[2] = cvtpk(a1.x, a1.y);
                    fr.u[3] = cvtpk(a1.z, a1.w);
                    frv[ks] = fr.v;
                }
            }
            const unsigned short* kr16 = Kb16 + (size_t)se.x * 128 + g4 * 4;

            // ---- MFMA: 8 head tiles + 1 bias tile, K=128, single pass ----
            f32x4 acc[8], accb;
            #pragma unroll
            for (int hh = 0; hh < 8; ++hh) acc[hh] = (f32x4){0.f, 0.f, 0.f, 0.f};
            accb = (f32x4){0.f, 0.f, 0.f, 0.f};
            #pragma unroll
            for (int ks = 0; ks < 4; ++ks) {
                const int kb = ks * 64 + kb_l;
                const bf16x8 abf = *(const bf16x8*)((char*)WbB + eloc * 256 + (kb ^ ((eloc & 7) << 4)));
                accb = __builtin_amdgcn_mfma_f32_16x16x32_bf16(abf, frv[ks], accb, 0, 0, 0);
                #pragma unroll
                for (int hh = 0; hh < 8; ++hh) {
                    const int ar = hh * 16 + eloc;
                    const bf16x8 af = *(const bf16x8*)((char*)WeB + ar * 256 + (kb ^ ((ar & 7) << 4)));
                    acc[hh] = __builtin_amdgcn_mfma_f32_16x16x32_bf16(af, frv[ks], acc[hh], 0, 0, 0);
                }
            }

            // ---- score epilogue: bf16 K * fp32 Q dot vs acc, reduce, exp --
            float scv[8];
            #pragma unroll
            for (int hh = 0; hh < 8; ++hh) {
                const uint2  k2 = *(const uint2*)(kr16 + hh * 16);
                const float4 qq = qv[hh];
                float m = acc[hh][0] * (bflo(k2.x) * qq.x)
                        + acc[hh][1] * (bfhi(k2.x) * qq.y)
                        + acc[hh][2] * (bflo(k2.y) * qq.z)
                        + acc[hh][3] * (bfhi(k2.y) * qq.w);
                m += __shfl_xor(m, 16);
                m += __shfl_xor(m, 32);
                const float eb = __shfl(accb[hh & 3], ((hh >> 2) << 4) | eloc);
                float sc = m * 0.25f + eb + bb[hh];
                sc = expf(fminf(fmaxf(sc, -5.f), 5.f));
                scv[hh] = (eloc < cnt) ? sc : 0.f;   // mask chunk tail
            }
            if (l < 16) {
                float4 s0 = {scv[0], scv[1], scv[2], scv[3]};
                float4 s1 = {scv[4], scv[5], scv[6], scv[7]};
                *(float4*)&scw[w][l][0] = s0;
                *(float4*)&scw[w][l][4] = s1;
                srw[w][l] = se.x;
            }
            asm volatile("s_waitcnt lgkmcnt(0)" ::: "memory");
            __builtin_amdgcn_sched_barrier(0);

            // ---- PV: halves alternate CSR slots; lane owns dims 4q..4q+3 --
            int e = half;
            for (; e + 2 < cnt; e += 4) {
                const int   s0 = srw[w][e],     s1 = srw[w][e + 2];
                const float c0 = scw[w][e][hq], c1 = scw[w][e + 2][hq];
                const uint2 u0 = *(const uint2*)(Vb16 + (size_t)s0 * 128 + 4 * q);
                const uint2 u1 = *(const uint2*)(Vb16 + (size_t)s1 * 128 + 4 * q);
                pv.x += bflo(u0.x) * c0 + bflo(u1.x) * c1;
                pv.y += bfhi(u0.x) * c0 + bfhi(u1.x) * c1;
                pv.z += bflo(u0.y) * c0 + bflo(u1.y) * c1;
                pv.w += bfhi(u0.y) * c0 + bfhi(u1.y) * c1;
                zz += c0 + c1;
            }
            for (; e < cnt; e += 2) {
                const int   s0 = srw[w][e];
                const float c0 = scw[w][e][hq];
                const uint2 u0 = *(const uint2*)(Vb16 + (size_t)s0 * 128 + 4 * q);
                pv.x += bflo(u0.x) * c0; pv.y += bfhi(u0.x) * c0;
                pv.z += bflo(u0.y) * c0; pv.w += bfhi(u0.y) * c0;
                zz += c0;
            }
        }

        // merge halves, write x row from half 0
        pv.x += __shfl_xor(pv.x, 32); pv.y += __shfl_xor(pv.y, 32);
        pv.z += __shfl_xor(pv.z, 32); pv.w += __shfl_xor(pv.w, 32);
        zz   += __shfl_xor(zz, 32);
        if (half == 0) {
            const float inv = 1.f / (zz + 1e-6f);
            const float4 hv = *(const float4*)&h[(size_t)node * 128 + 4 * q];
            float4 xv;
            xv.x = hv.x + pv.x * inv; xv.y = hv.y + pv.y * inv;
            xv.z = hv.z + pv.z * inv; xv.w = hv.w + pv.w * inv;
            *(float4*)&x[(size_t)node * 128 + 4 * q] = xv;
            sA.x += xv.x; sA.y += xv.y; sA.z += xv.z; sA.w += xv.w;
            sQ2.x += xv.x * xv.x; sQ2.y += xv.y * xv.y;
            sQ2.z += xv.z * xv.z; sQ2.w += xv.w * xv.w;
        }
    }

    // ---- stats: reuse WbB as scratch (all waves past the loop) ----
    __syncthreads();
    float* wbF = (float*)WbB;                   // 1024 floats
    if (half == 0) {
        *(float4*)&wbF[w * 256 + 4 * q]       = sA;
        *(float4*)&wbF[w * 256 + 128 + 4 * q] = sQ2;
    }
    __syncthreads();
    if (t < 128) {
        float s = 0.f, sq2 = 0.f;
        #pragma unroll
        for (int wi = 0; wi < 4; ++wi) {
            s   += wbF[wi * 256 + t];
            sq2 += wbF[wi * 256 + 128 + t];
        }
        atomicAdd(&stat[t], s);
        atomicAdd(&stat[128 + t], sq2);
    }
}

// ---------------------------------------------------------- BN params ------
__global__ void bn_params(const float* __restrict__ sum, const float* __restrict__ sumsq,
                          const float* __restrict__ gamma, const float* __restrict__ beta,
                          float* __restrict__ a, float* __restrict__ b, float invn)
{
    const int c = threadIdx.x;
    const float mean = sum[c] * invn;
    const float var  = sumsq[c] * invn - mean * mean;
    const float sc   = gamma[c] * rsqrtf(var + 1e-5f);
    a[c] = sc;
    b[c] = beta[c] - mean * sc;
}

// ---------------------------------------------------------------- FFN ------
__global__ __launch_bounds__(128)
void ffn_kernel(const float* __restrict__ x, const float* __restrict__ W1,
                const float* __restrict__ b1, const float* __restrict__ W2,
                const float* __restrict__ b2, const float* __restrict__ par,
                float* __restrict__ zb, float* __restrict__ stat2)
{
    __shared__ float xnl[16 * 128];
    __shared__ float hidl[16 * 256];
    const int t  = threadIdx.x;
    const int n0 = blockIdx.x * 16;

    const float4* xg4 = (const float4*)(x + (size_t)n0 * 128);
    const float4* a4  = (const float4*)par;
    const float4* bv4 = (const float4*)(par + 128);
    float4* xnl4 = (float4*)xnl;
    #pragma unroll
    for (int i = 0; i < 4; ++i) {
        const int idx = i * 128 + t;
        const float4 xv = xg4[idx];
        const float4 av = a4[idx & 31], bv = bv4[idx & 31];
        float4 r;
        r.x = xv.x * av.x + bv.x; r.y = xv.y * av.y + bv.y;
        r.z = xv.z * av.z + bv.z; r.w = xv.w * av.w + bv.w;
        xnl4[idx] = r;
    }
    __syncthreads();

    float acc0[16], acc1[16];
    #pragma unroll
    for (int n = 0; n < 16; ++n) { acc0[n] = 0.f; acc1[n] = 0.f; }
    const float* w0p = W1 + (size_t)t * 128;
    const float* w1p = W1 + (size_t)(t + 128) * 128;
    for (int kc = 0; kc < 32; ++kc) {
        const float4 w0 = *(const float4*)(w0p + kc * 4);
        const float4 w1 = *(const float4*)(w1p + kc * 4);
        #pragma unroll
        for (int n = 0; n < 16; ++n) {
            const float4 xv = *(const float4*)&xnl[n * 128 + kc * 4];
            acc0[n] += w0.x * xv.x + w0.y * xv.y + w0.z * xv.z + w0.w * xv.w;
            acc1[n] += w1.x * xv.x + w1.y * xv.y + w1.z * xv.z + w1.w * xv.w;
        }
    }
    const float bi0 = b1[t], bi1 = b1[t + 128];
    #pragma unroll
    for (int n = 0; n < 16; ++n) {
        hidl[n * 256 + t]       = fmaxf(acc0[n] + bi0, 0.f);
        hidl[n * 256 + 128 + t] = fmaxf(acc1[n] + bi1, 0.f);
    }
    __syncthreads();

    float acc2[16];
    #pragma unroll
    for (int n = 0; n < 16; ++n) acc2[n] = 0.f;
    const float* w2p = W2 + (size_t)t * 256;
    for (int kc = 0; kc < 64; ++kc) {
        const float4 w = *(const float4*)(w2p + kc * 4);
        #pragma unroll
        for (int n = 0; n < 16; ++n) {
            const float4 hv = *(const float4*)&hidl[n * 256 + kc * 4];
            acc2[n] += w.x * hv.x + w.y * hv.y + w.z * hv.z + w.w * hv.w;
        }
    }
    const float bi2 = b2[t];
    float s = 0.f, sq = 0.f;
    float* zo = zb + (size_t)n0 * 128 + t;
    #pragma unroll
    for (int n = 0; n < 16; ++n) {
        const float z = xnl[n * 128 + t] + acc2[n] + bi2;
        zo[(size_t)n * 128] = z;
        s += z; sq += z * z;
    }
    atomicAdd(&stat2[t], s);
    atomicAdd(&stat2[128 + t], sq);
}

// ---------------------------------------------------------- final BN -------
__global__ void final_bn(const float4* __restrict__ zb, const float* __restrict__ pa,
                         const float* __restrict__ pb, float4* __restrict__ out, int total4)
{
    const float4* a4 = (const float4*)pa;
    const float4* b4 = (const float4*)pb;
    const int stride = gridDim.x * blockDim.x;
    for (int i = blockIdx.x * blockDim.x + threadIdx.x; i < total4; i += stride) {
        const float4 z = zb[i];
        const float4 a = a4[i & 31], b = b4[i & 31];
        float4 r;
        r.x = z.x * a.x + b.x; r.y = z.y * a.y + b.y;
        r.z = z.z * a.z + b.z; r.w = z.w * a.w + b.w;
        out[i] = r;
    }
}

// ---------------------------------------------------------------------------
extern "C" void kernel_launch(void* const* d_in, const int* in_sizes, int n_in,
                              void* d_out, int out_size, void* d_ws, size_t ws_size,
                              hipStream_t stream)
{
    const float* h   = (const float*)d_in[0];
    const int*   ei  = (const int*)  d_in[1];
    const float* ea  = (const float*)d_in[2];
    const float* Wq  = (const float*)d_in[3];
    const float* Wk  = (const float*)d_in[4];
    const float* Wv  = (const float*)d_in[5];
    const float* We  = (const float*)d_in[6];
    const float* Wb  = (const float*)d_in[7];
    const float* bbv = (const float*)d_in[8];
    const float* g1  = (const float*)d_in[9];
    const float* be1 = (const float*)d_in[10];
    const float* W1  = (const float*)d_in[11];
    const float* b1  = (const float*)d_in[12];
    const float* W2  = (const float*)d_in[13];
    const float* b2  = (const float*)d_in[14];
    const float* g2  = (const float*)d_in[15];
    const float* be2 = (const float*)d_in[16];
    float* out = (float*)d_out;

    const int N   = in_sizes[0] / 128;
    const int EDG = in_sizes[1] / 2;
    const int NB  = (N + 1023) / 1024;
    const size_t nd = (size_t)N * 128;
    auto al8 = [](size_t v){ return (v + 7) & ~(size_t)7; };

    float* ws = (float*)d_ws;
    const size_t Qo  = 0;                            // Qb fp32; reused as z after fused_attn
    const size_t K16 = nd;                           // Kb16 (nd ushort = nd/2 slots)
    const size_t V16 = nd + nd / 2;                  // Vb16
    const size_t Xo  = 2 * nd;                       // x (attn output)
    const size_t ELo = 3 * nd;                       // elist (EDG int2)
    const size_t OFo = ELo + (size_t)EDG * 2;        // offs (N+1 int)
    const size_t CUo = al8(OFo + (size_t)N + 8);     // counts (N int)
    const size_t BSo = al8(CUo + (size_t)N);         // block sums (NB int)
    const size_t BBo = al8(BSo + (size_t)NB);        // block bases (NB int)
    const size_t STo = al8(BBo + (size_t)NB);        // stats: 512 f32
    const size_t PAR = STo + 512;                    // bn params: 512 f32

    int*  cnt   = (int*)(ws + CUo);
    int*  offs  = (int*)(ws + OFo);
    int*  bsum  = (int*)(ws + BSo);
    int*  bbase = (int*)(ws + BBo);
    int2* elist = (int2*)(ws + ELo);
    unsigned short* kb16 = (unsigned short*)(ws + K16);
    unsigned short* vb16 = (unsigned short*)(ws + V16);

    hipMemsetAsync(cnt, 0, (size_t)N * sizeof(int), stream);
    hipMemsetAsync(ws + STo, 0, 512 * sizeof(float), stream);

    qkv_kernel<<<N / 16, 128, 0, stream>>>(h, Wq, Wk, Wv, ws + Qo, kb16, vb16);

    hist_kernel<<<1024, 256, 0, stream>>>(ei, cnt, EDG);
    scan_a<<<NB, 1024, 0, stream>>>(cnt, bsum, N);
    scan_b<<<1, 64, 0, stream>>>(bsum, bbase, offs, NB, N);
    scan_c<<<NB, 1024, 0, stream>>>(cnt, bbase, offs, N);
    scatter_kernel<<<1024, 256, 0, stream>>>(ei, offs, cnt, elist, EDG);

    fused_attn<<<1024, 256, 0, stream>>>(ea, elist, offs, We, Wb, bbv,
                                         ws + Qo, kb16, vb16, h,
                                         ws + Xo, ws + STo, N, EDG);

    bn_params<<<1, 128, 0, stream>>>(ws + STo, ws + STo + 128, g1, be1,
                                     ws + PAR, ws + PAR + 128, 1.0f / (float)N);
    ffn_kernel<<<N / 16, 128, 0, stream>>>(ws + Xo, W1, b1, W2, b2, ws + PAR,
                                           ws + Qo, ws + STo + 256);
    bn_params<<<1, 128, 0, stream>>>(ws + STo + 256, ws + STo + 384, g2, be2,
                                     ws + PAR + 256, ws + PAR + 384, 1.0f / (float)N);
    final_bn<<<1024, 256, 0, stream>>>((const float4*)(ws + Qo), ws + PAR + 256,
                                       ws + PAR + 384, (float4*)out, N * 32);
}